// Round 1
// baseline (545.680 us; speedup 1.0000x reference)
//
#include <hip/hip_runtime.h>
#include <math.h>

#define LL 96
#define LP 768
#define BD 256
#define HD 128
#define NB 2
#define NEGV (-20.0f)

__device__ __forceinline__ float gelu_exact(float x) {
  return 0.5f * x * (1.0f + erff(x * 0.70710678118654752f));
}

// ---------------- pad-mask decode (uint8 vs int32 ambiguity) ----------------
__global__ void decode_pads_kernel(const void* lp, const void* pp,
                                   unsigned char* lmask, unsigned char* pmask) {
  __shared__ int bad;
  if (threadIdx.x == 0) bad = 0;
  __syncthreads();
  const unsigned int* li = (const unsigned int*)lp;
  const unsigned int* pi = (const unsigned int*)pp;
  for (int i = threadIdx.x; i < NB * LL; i += 256) if (li[i] > 1u) atomicOr(&bad, 1);
  for (int i = threadIdx.x; i < NB * LP; i += 256) if (pi[i] > 1u) atomicOr(&bad, 1);
  __syncthreads();
  const bool asInt = (bad == 0);
  const unsigned char* lb = (const unsigned char*)lp;
  const unsigned char* pb = (const unsigned char*)pp;
  for (int i = threadIdx.x; i < NB * LL; i += 256)
    lmask[i] = asInt ? (unsigned char)(li[i] != 0u) : (unsigned char)(lb[i] != 0);
  for (int i = threadIdx.x; i < NB * LP; i += 256)
    pmask[i] = asInt ? (unsigned char)(pi[i] != 0u) : (unsigned char)(pb[i] != 0);
}

// ------------- small projection GEMM: Y[M,N] = X[M,256]@W[256,N]+b ----------
template <int N>
__global__ __launch_bounds__(256) void proj_kernel(const float* __restrict__ X,
                                                   const float* __restrict__ W,
                                                   const float* __restrict__ bias,
                                                   float* __restrict__ Y) {
  __shared__ float Xs[16 * 256];
  const int tid = threadIdx.x;
  const int r0 = blockIdx.x * 16;
#pragma unroll
  for (int q = 0; q < 16; ++q) {
    int e = tid + q * 256;
    Xs[e] = X[r0 * 256 + e];
  }
  __syncthreads();
  const int c = tid % N;
  constexpr int RPT = N / 16;  // 256->16 rows/thread, 128->8
  const int rbase = (tid / N) * RPT;
  float bv = bias ? bias[c] : 0.0f;
  float acc[RPT];
#pragma unroll
  for (int i = 0; i < RPT; ++i) acc[i] = bv;
#pragma unroll 4
  for (int k = 0; k < 256; ++k) {
    float w = W[k * N + c];
#pragma unroll
    for (int i = 0; i < RPT; ++i) acc[i] = fmaf(Xs[(rbase + i) * 256 + k], w, acc[i]);
  }
#pragma unroll
  for (int i = 0; i < RPT; ++i) Y[(r0 + rbase + i) * N + c] = acc[i];
}

// ---------------- main pair kernel: 4 ligands x 16 proteins / block ---------
__global__ __launch_bounds__(256) void pair_kernel(
    const float* __restrict__ lbuf, const float* __restrict__ pbuf,
    const float* __restrict__ A1, const float* __restrict__ B1,
    const float* __restrict__ W1, const float* __restrict__ W2,
    const float* __restrict__ b2, const float* __restrict__ W3,
    const float* __restrict__ b3, const unsigned char* __restrict__ lmask,
    const unsigned char* __restrict__ pmask, float* __restrict__ logits) {
  __shared__ float sW[64 * 128];  // W1/W2 chunk [64 rows][128 cols]
  __shared__ float sB[64 * 128];  // phase1: F[64][64]+lt[4][64]+pt[16][64]; phase2: H[64][128]
  float* Fs = sB;
  float* lt = sB + 4096;
  float* pt = sB + 4096 + 256;
  float* Hs = sB;

  const int b = blockIdx.z;
  const int i0 = blockIdx.y * 4;
  const int j0 = blockIdx.x * 16;
  const int tid = threadIdx.x;
  const int tc = tid & 31;
  const int tr = tid >> 5;
  const int k0 = tc * 4;

  float acc[8][4];
#pragma unroll
  for (int pi = 0; pi < 8; ++pi)
#pragma unroll
    for (int kk = 0; kk < 4; ++kk) acc[pi][kk] = 0.0f;

  const float* lg = lbuf + (b * LL + i0) * BD;
  const float* pg = pbuf + (b * LP + j0) * BD;

  for (int c = 0; c < 8; ++c) {
    const int d0 = (c & 3) * 64;
    const int isU = (c >= 4) ? 1 : 0;
    {
      int r = tid >> 6, dd = tid & 63;
      lt[tid] = lg[r * BD + d0 + dd];
    }
#pragma unroll
    for (int q = 0; q < 4; ++q) {
      int e = tid + q * 256;
      int r = e >> 6, dd = e & 63;
      pt[e] = pg[r * BD + d0 + dd];
    }
    __syncthreads();
#pragma unroll
    for (int m = 0; m < 16; ++m) {
      int p = (tid >> 6) + 4 * m;
      int dd = tid & 63;
      float lv = lt[(p >> 4) * 64 + dd];
      float pv = pt[(p & 15) * 64 + dd];
      Fs[p * 64 + dd] = isU ? fabsf(lv - pv) : lv * pv;
    }
    const float* wg = W1 + (size_t)(512 + isU * 256 + d0) * HD;
#pragma unroll
    for (int q = 0; q < 32; ++q) sW[tid + q * 256] = wg[tid + q * 256];
    __syncthreads();
#pragma unroll 4
    for (int s = 0; s < 16; ++s) {
      const int base = s * 4;
      float wv[4][4];
#pragma unroll
      for (int q = 0; q < 4; ++q)
        *(float4*)&wv[q][0] = *(const float4*)&sW[(base + q) * HD + k0];
#pragma unroll
      for (int pi = 0; pi < 8; ++pi) {
        float fv[4];
        *(float4*)fv = *(const float4*)&Fs[(tr * 8 + pi) * 64 + base];
#pragma unroll
        for (int q = 0; q < 4; ++q)
#pragma unroll
          for (int kk = 0; kk < 4; ++kk)
            acc[pi][kk] = fmaf(fv[q], wv[q][kk], acc[pi][kk]);
      }
    }
    __syncthreads();
  }

  // epilogue layer1: + A1 + B1, gelu, write H
#pragma unroll
  for (int pi = 0; pi < 8; ++pi) {
    const int p = tr * 8 + pi;
    const int il = p >> 4, jl = p & 15;
    float4 a4 = *(const float4*)&A1[(size_t)(b * LL + i0 + il) * HD + k0];
    float4 b4 = *(const float4*)&B1[(size_t)(b * LP + j0 + jl) * HD + k0];
    float av[4] = {a4.x, a4.y, a4.z, a4.w};
    float bv[4] = {b4.x, b4.y, b4.z, b4.w};
    float hv[4];
#pragma unroll
    for (int kk = 0; kk < 4; ++kk) {
      float x = acc[pi][kk] + av[kk] + bv[kk];
      hv[kk] = gelu_exact(x);
    }
    *(float4*)&Hs[p * HD + k0] = *(float4*)hv;
  }
  __syncthreads();

  // layer 2
  float acc2[8][4];
  {
    float4 b2v = *(const float4*)&b2[k0];
    float bb[4] = {b2v.x, b2v.y, b2v.z, b2v.w};
#pragma unroll
    for (int pi = 0; pi < 8; ++pi)
#pragma unroll
      for (int kk = 0; kk < 4; ++kk) acc2[pi][kk] = bb[kk];
  }
  for (int c2 = 0; c2 < 2; ++c2) {
    const float* wg = W2 + (size_t)c2 * 64 * HD;
#pragma unroll
    for (int q = 0; q < 32; ++q) sW[tid + q * 256] = wg[tid + q * 256];
    __syncthreads();
#pragma unroll 4
    for (int s = 0; s < 16; ++s) {
      const int base = s * 4;
      float wv[4][4];
#pragma unroll
      for (int q = 0; q < 4; ++q)
        *(float4*)&wv[q][0] = *(const float4*)&sW[(base + q) * HD + k0];
#pragma unroll
      for (int pi = 0; pi < 8; ++pi) {
        float hv[4];
        *(float4*)hv = *(const float4*)&Hs[(tr * 8 + pi) * HD + c2 * 64 + base];
#pragma unroll
        for (int q = 0; q < 4; ++q)
#pragma unroll
          for (int kk = 0; kk < 4; ++kk)
            acc2[pi][kk] = fmaf(hv[q], wv[q][kk], acc2[pi][kk]);
      }
    }
    __syncthreads();
  }

  // layer 3 + reduce across the 32 k-columns
  float4 w3v = *(const float4*)&W3[k0];
  float w3a[4] = {w3v.x, w3v.y, w3v.z, w3v.w};
  float part[8];
#pragma unroll
  for (int pi = 0; pi < 8; ++pi) {
    float s = 0.0f;
#pragma unroll
    for (int kk = 0; kk < 4; ++kk) s = fmaf(gelu_exact(acc2[pi][kk]), w3a[kk], s);
    part[pi] = s;
  }
#pragma unroll
  for (int pi = 0; pi < 8; ++pi) {
#pragma unroll
    for (int m = 16; m > 0; m >>= 1) part[pi] += __shfl_xor(part[pi], m, 64);
  }
  if (tc == 0) {
    const float bb3 = b3[0];
#pragma unroll
    for (int pi = 0; pi < 8; ++pi) {
      const int p = tr * 8 + pi;
      const int i = i0 + (p >> 4), j = j0 + (p & 15);
      float v = part[pi] + bb3;
      if (isnan(v)) v = 0.0f;
      else if (isinf(v)) v = (v > 0.0f) ? 20.0f : NEGV;
      if (lmask[b * LL + i] || pmask[b * LP + j]) v = NEGV;
      logits[(size_t)b * LL * LP + i * LP + j] = v;
    }
  }
}

// ---------------- exact top-100 + softmax-weighted sum ----------------------
__device__ __forceinline__ unsigned int fkey(float f) {
  unsigned int u = __float_as_uint(f);
  return u ^ ((u >> 31) ? 0xFFFFFFFFu : 0x80000000u);
}
__device__ __forceinline__ float finv(unsigned int k) {
  unsigned int u = k ^ ((k >> 31) ? 0x80000000u : 0xFFFFFFFFu);
  return __uint_as_float(u);
}

__global__ __launch_bounds__(1024) void topk_kernel(const float* __restrict__ logits,
                                                    float* __restrict__ out) {
  const int N = LL * LP;
  const int b = blockIdx.x;
  const float* data = logits + (size_t)b * N;
  const int tid = threadIdx.x;
  __shared__ unsigned int hist[256];
  __shared__ unsigned int ured[1024];
  __shared__ float red[1024];
  __shared__ unsigned int sPrefix, sNeed;

  // global max (in key space)
  unsigned int km = 0u;
  for (int i = tid; i < N; i += 1024) km = max(km, fkey(data[i]));
  ured[tid] = km;
  __syncthreads();
  for (int s = 512; s > 0; s >>= 1) {
    if (tid < s) ured[tid] = max(ured[tid], ured[tid + s]);
    __syncthreads();
  }
  const float vmax = finv(ured[0]);

  if (tid == 0) { sPrefix = 0u; sNeed = 100u; }
  __syncthreads();

  for (int s = 24; s >= 0; s -= 8) {
    if (tid < 256) hist[tid] = 0u;
    __syncthreads();
    const unsigned int prefix = sPrefix;
    const unsigned int maskhi = (s == 24) ? 0u : (0xFFFFFFFFu << (s + 8));
    for (int i = tid; i < N; i += 1024) {
      unsigned int k = fkey(data[i]);
      if ((k & maskhi) == (prefix & maskhi)) atomicAdd(&hist[(k >> s) & 255], 1u);
    }
    __syncthreads();
    if (tid == 0) {
      unsigned int need = sNeed, cum = 0u;
      int dsel = 0;
      for (int d = 255; d >= 0; --d) {
        cum += hist[d];
        if (cum >= need) { dsel = d; break; }
      }
      sNeed = need - (cum - hist[dsel]);
      sPrefix = prefix | ((unsigned int)dsel << s);
    }
    __syncthreads();
  }
  const unsigned int Tkey = sPrefix;
  const unsigned int needT = sNeed;  // # of values == T inside the top-100
  const float T = finv(Tkey);

  float s1 = 0.0f, s2 = 0.0f;
  for (int i = tid; i < N; i += 1024) {
    float v = data[i];
    if (fkey(v) > Tkey) {
      float e = expf(v - vmax);
      s1 += e;
      s2 = fmaf(e, v, s2);
    }
  }
  red[tid] = s1;
  __syncthreads();
  for (int s = 512; s > 0; s >>= 1) {
    if (tid < s) red[tid] += red[tid + s];
    __syncthreads();
  }
  float s1t = red[0];
  __syncthreads();
  red[tid] = s2;
  __syncthreads();
  for (int s = 512; s > 0; s >>= 1) {
    if (tid < s) red[tid] += red[tid + s];
    __syncthreads();
  }
  if (tid == 0) {
    float s2t = red[0];
    float e = expf(T - vmax);
    float denom = s1t + (float)needT * e;
    float num = s2t + (float)needT * e * T;
    out[b] = num / denom;
  }
}

// ---------------------------------------------------------------------------
extern "C" void kernel_launch(void* const* d_in, const int* in_sizes, int n_in,
                              void* d_out, int out_size, void* d_ws, size_t ws_size,
                              hipStream_t stream) {
  const float* l_tok = (const float*)d_in[0];
  const float* p_tok = (const float*)d_in[1];
  const void* l_pad = d_in[2];
  const void* p_pad = d_in[3];
  const float* Wl = (const float*)d_in[4];
  const float* bl = (const float*)d_in[5];
  const float* Wp = (const float*)d_in[6];
  const float* bp = (const float*)d_in[7];
  const float* W1 = (const float*)d_in[8];
  const float* b1 = (const float*)d_in[9];
  const float* W2 = (const float*)d_in[10];
  const float* b2 = (const float*)d_in[11];
  const float* W3 = (const float*)d_in[12];
  const float* b3 = (const float*)d_in[13];

  float* ws = (float*)d_ws;
  float* wl_ = ws;                    // l:  [2,96,256]   49152
  float* wp_ = ws + 49152;            // p:  [2,768,256]  393216
  float* wA = ws + 442368;            // A1: [2,96,128]   24576
  float* wB = ws + 466944;            // B1: [2,768,128]  196608
  float* wLog = ws + 663552;          // logits: [2,73728] 147456
  unsigned char* lmask = (unsigned char*)(ws + 811008);
  unsigned char* pmask = lmask + NB * LL;

  decode_pads_kernel<<<1, 256, 0, stream>>>(l_pad, p_pad, lmask, pmask);
  proj_kernel<256><<<NB * LL / 16, 256, 0, stream>>>(l_tok, Wl, bl, wl_);
  proj_kernel<256><<<NB * LP / 16, 256, 0, stream>>>(p_tok, Wp, bp, wp_);
  proj_kernel<128><<<NB * LL / 16, 256, 0, stream>>>(wl_, W1, b1, wA);
  proj_kernel<128><<<NB * LP / 16, 256, 0, stream>>>(wp_, W1 + 256 * 128, nullptr, wB);

  dim3 grid(LP / 16, LL / 4, NB);
  pair_kernel<<<grid, 256, 0, stream>>>(wl_, wp_, wA, wB, W1, W2, b2, W3, b3,
                                        lmask, pmask, wLog);
  topk_kernel<<<NB, 1024, 0, stream>>>(wLog, (float*)d_out);
}

// Round 2
// 305.764 us; speedup vs baseline: 1.7846x; 1.7846x over previous
//
#include <hip/hip_runtime.h>
#include <hip/hip_bf16.h>
#include <math.h>

#define LL 96
#define LP 768
#define BD 256
#define HD 128
#define NB 2
#define NEGV (-20.0f)
#define LB 8    // ligands per block
#define PB 16   // proteins per block

typedef __attribute__((ext_vector_type(4))) float f32x4;
typedef __attribute__((ext_vector_type(8))) short s16x8;

__device__ __forceinline__ float gelu_exact(float x) {
  return 0.5f * x * (1.0f + erff(x * 0.70710678118654752f));
}

__device__ __forceinline__ f32x4 mfma16(s16x8 a, s16x8 b, f32x4 c) {
  return __builtin_amdgcn_mfma_f32_16x16x32_bf16(a, b, c, 0, 0, 0);
}

__device__ __forceinline__ unsigned pack_bf16(float a, float b) {
  float2 t; t.x = a; t.y = b;
  __hip_bfloat162 h = __float22bfloat162_rn(t);
  return *reinterpret_cast<unsigned*>(&h);
}

__device__ __forceinline__ unsigned short bfbits(float x) {
  __hip_bfloat16 h = __float2bfloat16(x);
  return *reinterpret_cast<unsigned short*>(&h);
}

// ---------------- pad-mask decode (uint8 vs int32 ambiguity) ----------------
__global__ void decode_pads_kernel(const void* lp, const void* pp,
                                   unsigned char* lmask, unsigned char* pmask) {
  __shared__ int bad;
  if (threadIdx.x == 0) bad = 0;
  __syncthreads();
  const unsigned int* li = (const unsigned int*)lp;
  const unsigned int* pi = (const unsigned int*)pp;
  for (int i = threadIdx.x; i < NB * LL; i += 256) if (li[i] > 1u) atomicOr(&bad, 1);
  for (int i = threadIdx.x; i < NB * LP; i += 256) if (pi[i] > 1u) atomicOr(&bad, 1);
  __syncthreads();
  const bool asInt = (bad == 0);
  const unsigned char* lb = (const unsigned char*)lp;
  const unsigned char* pb = (const unsigned char*)pp;
  for (int i = threadIdx.x; i < NB * LL; i += 256)
    lmask[i] = asInt ? (unsigned char)(li[i] != 0u) : (unsigned char)(lb[i] != 0);
  for (int i = threadIdx.x; i < NB * LP; i += 256)
    pmask[i] = asInt ? (unsigned char)(pi[i] != 0u) : (unsigned char)(pb[i] != 0);
}

// ---------- weight swizzle into MFMA fragment order (bf16) ------------------
// W1xf[c][kt][mt][lane][j] = bf16(W1[(512 + c*64 + kt*32 + (lane>>4)*8 + j)*128 + mt*16 + (lane&15)])
// W2f [kt][mt][lane][j]    = bf16(W2[(kt*32 + (lane>>4)*8 + j)*128 + mt*16 + (lane&15)])
__global__ __launch_bounds__(256) void swizzle_w_kernel(const float* __restrict__ W1,
                                                        const float* __restrict__ W2,
                                                        unsigned short* __restrict__ W1xf,
                                                        unsigned short* __restrict__ W2f) {
  int idx = blockIdx.x * 256 + threadIdx.x;
  if (idx < 65536) {
    int j = idx & 7, ln = (idx >> 3) & 63;
    int rest = idx >> 9;
    int mt = rest & 7, kt = (rest >> 3) & 1, cc = rest >> 4;
    int row = 512 + cc * 64 + kt * 32 + ((ln >> 4) << 3) + j;
    int col = mt * 16 + (ln & 15);
    W1xf[idx] = bfbits(W1[row * HD + col]);
  } else if (idx < 65536 + 16384) {
    int e = idx - 65536;
    int j = e & 7, ln = (e >> 3) & 63, mt = (e >> 9) & 7, kt = e >> 12;
    int row = kt * 32 + ((ln >> 4) << 3) + j;
    int col = mt * 16 + (ln & 15);
    W2f[e] = bfbits(W2[row * HD + col]);
  }
}

// ------------- small projection GEMM: Y[M,N] = X[M,256]@W[256,N]+b ----------
template <int N>
__global__ __launch_bounds__(256) void proj_kernel(const float* __restrict__ X,
                                                   const float* __restrict__ W,
                                                   const float* __restrict__ bias,
                                                   float* __restrict__ Y) {
  __shared__ float Xs[16 * 256];
  const int tid = threadIdx.x;
  const int r0 = blockIdx.x * 16;
#pragma unroll
  for (int q = 0; q < 16; ++q) {
    int e = tid + q * 256;
    Xs[e] = X[r0 * 256 + e];
  }
  __syncthreads();
  const int c = tid % N;
  constexpr int RPT = N / 16;
  const int rbase = (tid / N) * RPT;
  float bv = bias ? bias[c] : 0.0f;
  float acc[RPT];
#pragma unroll
  for (int i = 0; i < RPT; ++i) acc[i] = bv;
#pragma unroll 4
  for (int k = 0; k < 256; ++k) {
    float w = W[k * N + c];
#pragma unroll
    for (int i = 0; i < RPT; ++i) acc[i] = fmaf(Xs[(rbase + i) * 256 + k], w, acc[i]);
  }
#pragma unroll
  for (int i = 0; i < RPT; ++i) Y[(r0 + rbase + i) * N + c] = acc[i];
}

// ---------------- MFMA pair kernel: 8 ligands x 16 proteins / block ---------
// Computes D[hid][pair] transposed-GEMM form:
//   layer1: D1 = W1x^T(A) @ F(B),  A-frags from global (pre-swizzled), F built in LDS
//   layer2: D2 = W2^T(A)  @ H(B),  H written to LDS in B-fragment order
__global__ __launch_bounds__(256, 3) void pair_mfma_kernel(
    const float* __restrict__ lbuf, const float* __restrict__ pbuf,
    const float* __restrict__ A1, const float* __restrict__ B1,
    const unsigned short* __restrict__ W1xf, const unsigned short* __restrict__ W2f,
    const float* __restrict__ b2, const float* __restrict__ W3,
    const float* __restrict__ b3, const unsigned char* __restrict__ lmask,
    const unsigned char* __restrict__ pmask, float* __restrict__ logits) {
  // U: phase1 = lt[8][68] (0..543) + pt[16][68] (544..1631) + F frags (1632..5727)
  //    phase2 = H frags [kt4][nt8][64 lanes][8 bf16] = 8192 floats
  __shared__ float U[8192];
  __shared__ float A1s[LB * 132];
  __shared__ float B1s[PB * 132];
  __shared__ float b2s[HD];
  __shared__ float w3s[HD];
  __shared__ float redbuf[128];

  const int tid = threadIdx.x;
  const int lane = tid & 63;
  const int w = tid >> 6;
  const int g = lane >> 4;
  const int c = lane & 15;
  const int wm = w >> 1;  // hid half
  const int wn = w & 1;   // pair half
  const int bb = blockIdx.z;
  const int i0 = blockIdx.y * LB;
  const int j0 = blockIdx.x * PB;

  // stage per-block biases / weights
#pragma unroll
  for (int q = 0; q < 4; ++q) {
    int idx = tid + q * 256;  // 1024 = 8*128
    int row = idx >> 7, col = idx & 127;
    A1s[row * 132 + col] = A1[(size_t)(bb * LL + i0 + row) * HD + col];
  }
#pragma unroll
  for (int q = 0; q < 8; ++q) {
    int idx = tid + q * 256;  // 2048 = 16*128
    int row = idx >> 7, col = idx & 127;
    B1s[row * 132 + col] = B1[(size_t)(bb * LP + j0 + row) * HD + col];
  }
  if (tid < 128) b2s[tid] = b2[tid];
  else w3s[tid - 128] = W3[tid - 128];

  f32x4 acc1[4][4];
#pragma unroll
  for (int m = 0; m < 4; ++m)
#pragma unroll
    for (int n = 0; n < 4; ++n) acc1[m][n] = (f32x4)0.0f;

  const unsigned short* Fush = (const unsigned short*)&U[1632];
  unsigned* Fdw = (unsigned*)&U[1632];

  for (int c8 = 0; c8 < 8; ++c8) {
    const int dbase = (c8 & 3) * 64;
    const bool isU = (c8 < 4);

    // prefetch this chunk's A-fragments (W1x) from global — no LDS dependency
    s16x8 afr[2][4];
#pragma unroll
    for (int kt = 0; kt < 2; ++kt)
#pragma unroll
      for (int m = 0; m < 4; ++m)
        afr[kt][m] = *(const s16x8*)(W1xf +
            (size_t)((((c8 * 2 + kt) * 8) + (wm * 4 + m)) * 64 + lane) * 8);

    __syncthreads();  // prev MFMA done reading F; prev F-build done reading lt/pt
    // stage lt (8x64) and pt (16x64) fp32 slices
#pragma unroll
    for (int q = 0; q < 2; ++q) {
      int idx = tid + q * 256;
      int row = idx >> 6, dd = idx & 63;
      U[row * 68 + dd] = lbuf[(size_t)(bb * LL + i0 + row) * BD + dbase + dd];
    }
#pragma unroll
    for (int q = 0; q < 4; ++q) {
      int idx = tid + q * 256;
      int row = idx >> 6, dd = idx & 63;
      U[544 + row * 68 + dd] = pbuf[(size_t)(bb * LP + j0 + row) * BD + dbase + dd];
    }
    __syncthreads();

    // F-build: 16 fragments [kt2][pt8][64][8] in B-frag order
#pragma unroll
    for (int f = 0; f < 4; ++f) {
      int gidx = tid + f * 256;
      int frag = gidx >> 6;
      int ln = gidx & 63;
      int kt = frag >> 3, pt2 = frag & 7;
      int kc0 = kt * 32 + ((ln >> 4) << 3);
      const float* lrow = &U[pt2 * 68 + kc0];
      const float* prow = &U[544 + (ln & 15) * 68 + kc0];
      f32x4 l0 = *(const f32x4*)lrow;
      f32x4 l1 = *(const f32x4*)(lrow + 4);
      f32x4 p0 = *(const f32x4*)prow;
      f32x4 p1 = *(const f32x4*)(prow + 4);
      float x[8];
      if (isU) {
#pragma unroll
        for (int q = 0; q < 4; ++q) { x[q] = l0[q] * p0[q]; x[4 + q] = l1[q] * p1[q]; }
      } else {
#pragma unroll
        for (int q = 0; q < 4; ++q) { x[q] = fabsf(l0[q] - p0[q]); x[4 + q] = fabsf(l1[q] - p1[q]); }
      }
      unsigned* dst = &Fdw[(frag * 64 + ln) * 4];
      dst[0] = pack_bf16(x[0], x[1]);
      dst[1] = pack_bf16(x[2], x[3]);
      dst[2] = pack_bf16(x[4], x[5]);
      dst[3] = pack_bf16(x[6], x[7]);
    }
    __syncthreads();

    // MFMA over this chunk (K=64, 2 ktiles)
#pragma unroll
    for (int kt = 0; kt < 2; ++kt) {
#pragma unroll
      for (int n = 0; n < 4; ++n) {
        s16x8 bf = *((const s16x8*)Fush + ((kt * 8 + (wn * 4 + n)) * 64 + lane));
#pragma unroll
        for (int m = 0; m < 4; ++m) acc1[m][n] = mfma16(afr[kt][m], bf, acc1[m][n]);
      }
    }
  }

  __syncthreads();  // all F reads done before H overwrites U

  // epilogue layer1: h = gelu(D1 + A1[il] + B1[jl]); write H in layer2-B-frag order
  unsigned* Hdw = (unsigned*)U;
#pragma unroll
  for (int m = 0; m < 4; ++m) {
    const int hidM = wm * 4 + m;
    const int kt = (4 * hidM + g) >> 3;
    const int l2 = ((2 * hidM + (g >> 1)) & 3) * 16 + c;
    const int jd = (g & 1) * 2;
#pragma unroll
    for (int n = 0; n < 4; ++n) {
      const int ntg = wn * 4 + n;
      f32x4 a1v = *(const f32x4*)&A1s[ntg * 132 + hidM * 16 + g * 4];
      f32x4 b1v = *(const f32x4*)&B1s[c * 132 + hidM * 16 + g * 4];
      float h0 = gelu_exact(acc1[m][n][0] + a1v[0] + b1v[0]);
      float h1 = gelu_exact(acc1[m][n][1] + a1v[1] + b1v[1]);
      float h2 = gelu_exact(acc1[m][n][2] + a1v[2] + b1v[2]);
      float h3 = gelu_exact(acc1[m][n][3] + a1v[3] + b1v[3]);
      int base = ((kt * 8 + ntg) * 64 + l2) * 4 + jd;
      Hdw[base] = pack_bf16(h0, h1);
      Hdw[base + 1] = pack_bf16(h2, h3);
    }
  }
  __syncthreads();

  // layer 2: D2[hid2][pair] = W2^T @ H
  f32x4 acc2[4][4];
#pragma unroll
  for (int m = 0; m < 4; ++m)
#pragma unroll
    for (int n = 0; n < 4; ++n) acc2[m][n] = (f32x4)0.0f;

  const unsigned short* Hush = (const unsigned short*)U;
#pragma unroll
  for (int kt = 0; kt < 4; ++kt) {
    s16x8 a2[4];
#pragma unroll
    for (int m = 0; m < 4; ++m)
      a2[m] = *(const s16x8*)(W2f + (size_t)((kt * 8 + (wm * 4 + m)) * 64 + lane) * 8);
#pragma unroll
    for (int n = 0; n < 4; ++n) {
      s16x8 bf = *((const s16x8*)Hush + ((kt * 8 + (wn * 4 + n)) * 64 + lane));
#pragma unroll
      for (int m = 0; m < 4; ++m) acc2[m][n] = mfma16(a2[m], bf, acc2[m][n]);
    }
  }

  // epilogue layer2 + layer3 dot with W3
  float partial[4] = {0.0f, 0.0f, 0.0f, 0.0f};
#pragma unroll
  for (int m = 0; m < 4; ++m) {
    const int hb = (wm * 4 + m) * 16 + g * 4;
    f32x4 b2v = *(const f32x4*)&b2s[hb];
    f32x4 w3v = *(const f32x4*)&w3s[hb];
#pragma unroll
    for (int n = 0; n < 4; ++n) {
#pragma unroll
      for (int r = 0; r < 4; ++r)
        partial[n] = fmaf(gelu_exact(acc2[m][n][r] + b2v[r]), w3v[r], partial[n]);
    }
  }
#pragma unroll
  for (int n = 0; n < 4; ++n) {
    partial[n] += __shfl_xor(partial[n], 16, 64);
    partial[n] += __shfl_xor(partial[n], 32, 64);
  }
  if (wm == 0 && g == 0) {
#pragma unroll
    for (int n = 0; n < 4; ++n) redbuf[wn * 64 + n * 16 + c] = partial[n];
  }
  __syncthreads();
  if (wm == 1 && g == 0) {
    const float bb3 = b3[0];
#pragma unroll
    for (int n = 0; n < 4; ++n) {
      const int ntg = wn * 4 + n;
      float v = partial[n] + redbuf[wn * 64 + n * 16 + c] + bb3;
      if (isnan(v)) v = 0.0f;
      else if (isinf(v)) v = (v > 0.0f) ? 20.0f : NEGV;
      const int i = i0 + ntg, j = j0 + c;
      if (lmask[bb * LL + i] || pmask[bb * LP + j]) v = NEGV;
      logits[(size_t)bb * LL * LP + i * LP + j] = v;
    }
  }
}

// ---------------- exact top-100 + softmax-weighted sum ----------------------
__device__ __forceinline__ unsigned int fkey(float f) {
  unsigned int u = __float_as_uint(f);
  return u ^ ((u >> 31) ? 0xFFFFFFFFu : 0x80000000u);
}
__device__ __forceinline__ float finv(unsigned int k) {
  unsigned int u = k ^ ((k >> 31) ? 0x80000000u : 0xFFFFFFFFu);
  return __uint_as_float(u);
}

__global__ __launch_bounds__(1024) void topk_kernel(const float* __restrict__ logits,
                                                    float* __restrict__ out) {
  const int N = LL * LP;
  const int b = blockIdx.x;
  const float* data = logits + (size_t)b * N;
  const int tid = threadIdx.x;
  __shared__ unsigned int hist[256];
  __shared__ unsigned int ured[1024];
  __shared__ float red[1024];
  __shared__ unsigned int sPrefix, sNeed;

  unsigned int km = 0u;
  for (int i = tid; i < N; i += 1024) km = max(km, fkey(data[i]));
  ured[tid] = km;
  __syncthreads();
  for (int s = 512; s > 0; s >>= 1) {
    if (tid < s) ured[tid] = max(ured[tid], ured[tid + s]);
    __syncthreads();
  }
  const float vmax = finv(ured[0]);

  if (tid == 0) { sPrefix = 0u; sNeed = 100u; }
  __syncthreads();

  for (int s = 24; s >= 0; s -= 8) {
    if (tid < 256) hist[tid] = 0u;
    __syncthreads();
    const unsigned int prefix = sPrefix;
    const unsigned int maskhi = (s == 24) ? 0u : (0xFFFFFFFFu << (s + 8));
    for (int i = tid; i < N; i += 1024) {
      unsigned int k = fkey(data[i]);
      if ((k & maskhi) == (prefix & maskhi)) atomicAdd(&hist[(k >> s) & 255], 1u);
    }
    __syncthreads();
    if (tid == 0) {
      unsigned int need = sNeed, cum = 0u;
      int dsel = 0;
      for (int d = 255; d >= 0; --d) {
        cum += hist[d];
        if (cum >= need) { dsel = d; break; }
      }
      sNeed = need - (cum - hist[dsel]);
      sPrefix = prefix | ((unsigned int)dsel << s);
    }
    __syncthreads();
  }
  const unsigned int Tkey = sPrefix;
  const unsigned int needT = sNeed;
  const float T = finv(Tkey);

  float s1 = 0.0f, s2 = 0.0f;
  for (int i = tid; i < N; i += 1024) {
    float v = data[i];
    if (fkey(v) > Tkey) {
      float e = expf(v - vmax);
      s1 += e;
      s2 = fmaf(e, v, s2);
    }
  }
  red[tid] = s1;
  __syncthreads();
  for (int s = 512; s > 0; s >>= 1) {
    if (tid < s) red[tid] += red[tid + s];
    __syncthreads();
  }
  float s1t = red[0];
  __syncthreads();
  red[tid] = s2;
  __syncthreads();
  for (int s = 512; s > 0; s >>= 1) {
    if (tid < s) red[tid] += red[tid + s];
    __syncthreads();
  }
  if (tid == 0) {
    float s2t = red[0];
    float e = expf(T - vmax);
    float denom = s1t + (float)needT * e;
    float num = s2t + (float)needT * e * T;
    out[b] = num / denom;
  }
}

// ---------------------------------------------------------------------------
extern "C" void kernel_launch(void* const* d_in, const int* in_sizes, int n_in,
                              void* d_out, int out_size, void* d_ws, size_t ws_size,
                              hipStream_t stream) {
  const float* l_tok = (const float*)d_in[0];
  const float* p_tok = (const float*)d_in[1];
  const void* l_pad = d_in[2];
  const void* p_pad = d_in[3];
  const float* Wl = (const float*)d_in[4];
  const float* bl = (const float*)d_in[5];
  const float* Wp = (const float*)d_in[6];
  const float* bp = (const float*)d_in[7];
  const float* W1 = (const float*)d_in[8];
  const float* b1 = (const float*)d_in[9];
  const float* W2 = (const float*)d_in[10];
  const float* b2 = (const float*)d_in[11];
  const float* W3 = (const float*)d_in[12];
  const float* b3 = (const float*)d_in[13];

  float* ws = (float*)d_ws;
  float* wl_ = ws;                    // [2,96,256]   49152
  float* wp_ = ws + 49152;            // [2,768,256]  393216
  float* wA = ws + 442368;            // A1: [2,96,128]
  float* wB = ws + 466944;            // B1: [2,768,128]
  float* wLog = ws + 663552;          // logits [2,73728]
  unsigned char* lmask = (unsigned char*)(ws + 811008);
  unsigned char* pmask = lmask + NB * LL;
  unsigned short* W1xf = (unsigned short*)(ws + 811520);  // 65536 u16
  unsigned short* W2f = (unsigned short*)(ws + 844288);   // 16384 u16

  decode_pads_kernel<<<1, 256, 0, stream>>>(l_pad, p_pad, lmask, pmask);
  swizzle_w_kernel<<<320, 256, 0, stream>>>(W1, W2, W1xf, W2f);
  proj_kernel<256><<<NB * LL / 16, 256, 0, stream>>>(l_tok, Wl, bl, wl_);
  proj_kernel<256><<<NB * LP / 16, 256, 0, stream>>>(p_tok, Wp, bp, wp_);
  proj_kernel<128><<<NB * LL / 16, 256, 0, stream>>>(wl_, W1, b1, wA);
  proj_kernel<128><<<NB * LP / 16, 256, 0, stream>>>(wp_, W1 + 256 * 128, nullptr, wB);

  dim3 grid(LP / PB, LL / LB, NB);
  pair_mfma_kernel<<<grid, 256, 0, stream>>>(wl_, wp_, wA, wB, W1xf, W2f,
                                             b2, W3, b3, lmask, pmask, wLog);
  topk_kernel<<<NB, 1024, 0, stream>>>(wLog, (float*)d_out);
}

// Round 3
// 257.445 us; speedup vs baseline: 2.1196x; 1.1877x over previous
//
#include <hip/hip_runtime.h>
#include <hip/hip_bf16.h>
#include <math.h>

#define LL 96
#define LP 768
#define BD 256
#define HD 128
#define NB 2
#define NEGV (-20.0f)
#define LB 8    // ligands per block
#define PB 16   // proteins per block

typedef __attribute__((ext_vector_type(4))) float f32x4;
typedef __attribute__((ext_vector_type(4))) unsigned int u32x4;
typedef __attribute__((ext_vector_type(8))) short s16x8;

// Abramowitz-Stegun 7.1.26 erf, |err| <= 1.5e-7 absolute. ~14 VALU ops.
__device__ __forceinline__ float gelu_fast(float x) {
  float ax = fabsf(x) * 0.70710678118654752f;
  float t = 1.0f / fmaf(0.3275911f, ax, 1.0f);
  float poly = t * fmaf(t, fmaf(t, fmaf(t, fmaf(t, 1.061405429f, -1.453152027f),
                                        1.421413741f), -0.284496736f), 0.254829592f);
  float e = __expf(-ax * ax);
  float erfax = fmaf(-poly, e, 1.0f);
  float erfx = copysignf(erfax, x);
  return 0.5f * x * (1.0f + erfx);
}

__device__ __forceinline__ f32x4 mfma16(s16x8 a, s16x8 b, f32x4 c) {
  return __builtin_amdgcn_mfma_f32_16x16x32_bf16(a, b, c, 0, 0, 0);
}

__device__ __forceinline__ unsigned pack_bf16(float a, float b) {
  float2 t; t.x = a; t.y = b;
  __hip_bfloat162 h = __float22bfloat162_rn(t);
  return *reinterpret_cast<unsigned*>(&h);
}

__device__ __forceinline__ unsigned short bfbits(float x) {
  __hip_bfloat16 h = __float2bfloat16(x);
  return *reinterpret_cast<unsigned short*>(&h);
}

// ---------- fused: pad decode (block 0) + weight swizzle (blocks 1..320) ----
__global__ __launch_bounds__(256) void decode_swz_kernel(
    const void* lp, const void* pp, unsigned char* lmask, unsigned char* pmask,
    const float* __restrict__ W1, const float* __restrict__ W2,
    unsigned short* __restrict__ W1xf, unsigned short* __restrict__ W2f) {
  const int tid = threadIdx.x;
  if (blockIdx.x == 0) {
    __shared__ int bad;
    if (tid == 0) bad = 0;
    __syncthreads();
    const unsigned int* li = (const unsigned int*)lp;
    const unsigned int* pi = (const unsigned int*)pp;
    for (int i = tid; i < NB * LL; i += 256) if (li[i] > 1u) atomicOr(&bad, 1);
    for (int i = tid; i < NB * LP; i += 256) if (pi[i] > 1u) atomicOr(&bad, 1);
    __syncthreads();
    const bool asInt = (bad == 0);
    const unsigned char* lb = (const unsigned char*)lp;
    const unsigned char* pb = (const unsigned char*)pp;
    for (int i = tid; i < NB * LL; i += 256)
      lmask[i] = asInt ? (unsigned char)(li[i] != 0u) : (unsigned char)(lb[i] != 0);
    for (int i = tid; i < NB * LP; i += 256)
      pmask[i] = asInt ? (unsigned char)(pi[i] != 0u) : (unsigned char)(pb[i] != 0);
  } else {
    int idx = (blockIdx.x - 1) * 256 + tid;
    if (idx < 65536) {
      int j = idx & 7, ln = (idx >> 3) & 63;
      int rest = idx >> 9;
      int mt = rest & 7, kt = (rest >> 3) & 1, cc = rest >> 4;
      int row = 512 + cc * 64 + kt * 32 + ((ln >> 4) << 3) + j;
      int col = mt * 16 + (ln & 15);
      W1xf[idx] = bfbits(W1[row * HD + col]);
    } else if (idx < 65536 + 16384) {
      int e = idx - 65536;
      int j = e & 7, ln = (e >> 3) & 63, mt = (e >> 9) & 7, kt = e >> 12;
      int row = kt * 32 + ((ln >> 4) << 3) + j;
      int col = mt * 16 + (ln & 15);
      W2f[e] = bfbits(W2[row * HD + col]);
    }
  }
}

// ---------- fused projection chain: X@W+b -> Y1; Y1@W1part(+b1) -> Y2 -------
// blocks [0,12): ligand tiles; [12,108): protein tiles; 16 rows per block
__global__ __launch_bounds__(256) void fused_proj_kernel(
    const float* __restrict__ l_tok, const float* __restrict__ p_tok,
    const float* __restrict__ Wl, const float* __restrict__ bl,
    const float* __restrict__ Wp, const float* __restrict__ bp,
    const float* __restrict__ W1, const float* __restrict__ b1,
    float* __restrict__ wl_, float* __restrict__ wp_,
    float* __restrict__ wA, float* __restrict__ wB) {
  __shared__ float Xs[16 * 256];
  __shared__ float Ys[16 * 256];
  const int tid = threadIdx.x;
  const bool isL = blockIdx.x < (NB * LL / 16);
  const int blk = isL ? blockIdx.x : (blockIdx.x - NB * LL / 16);
  const int r0 = blk * 16;
  const float* X = isL ? l_tok : p_tok;
  const float* W = isL ? Wl : Wp;
  const float* bias = isL ? bl : bp;
  float* Y1 = isL ? wl_ : wp_;
  float* Y2 = isL ? wA : wB;
  const float* W1p = isL ? W1 : (W1 + 256 * HD);

#pragma unroll
  for (int q = 0; q < 16; ++q)
    Xs[tid + q * 256] = X[(size_t)r0 * 256 + tid + q * 256];
  __syncthreads();

  // phase A: full 256-col projection; thread owns column tid, 16 rows
  {
    const int cc = tid;
    float bv = bias[cc];
    float acc[16];
#pragma unroll
    for (int i = 0; i < 16; ++i) acc[i] = bv;
    for (int k4 = 0; k4 < 256; k4 += 4) {
      float wv[4];
#pragma unroll
      for (int q = 0; q < 4; ++q) wv[q] = W[(size_t)(k4 + q) * 256 + cc];
#pragma unroll
      for (int i = 0; i < 16; ++i) {
        f32x4 xv = *(const f32x4*)&Xs[i * 256 + k4];
#pragma unroll
        for (int q = 0; q < 4; ++q) acc[i] = fmaf(xv[q], wv[q], acc[i]);
      }
    }
#pragma unroll
    for (int i = 0; i < 16; ++i) {
      Y1[(size_t)(r0 + i) * 256 + cc] = acc[i];
      Ys[i * 256 + cc] = acc[i];
    }
  }
  __syncthreads();

  // phase B: 128-col projection of Y1; thread owns (col=tid&127, 8 rows)
  {
    const int c2 = tid & 127;
    const int half = tid >> 7;
    float bv = isL ? b1[c2] : 0.0f;
    float acc[8];
#pragma unroll
    for (int i = 0; i < 8; ++i) acc[i] = bv;
    for (int k4 = 0; k4 < 256; k4 += 4) {
      float wv[4];
#pragma unroll
      for (int q = 0; q < 4; ++q) wv[q] = W1p[(size_t)(k4 + q) * HD + c2];
#pragma unroll
      for (int i = 0; i < 8; ++i) {
        f32x4 yv = *(const f32x4*)&Ys[(half * 8 + i) * 256 + k4];
#pragma unroll
        for (int q = 0; q < 4; ++q) acc[i] = fmaf(yv[q], wv[q], acc[i]);
      }
    }
#pragma unroll
    for (int i = 0; i < 8; ++i)
      Y2[(size_t)(r0 + half * 8 + i) * HD + c2] = acc[i];
  }
}

// ---------------- MFMA pair kernel, 4-iteration pipelined version -----------
// Per d-chunk (64 wide): build BOTH mul and absdiff fragments, MFMA both.
// lt/pt double-buffered via reg staging issued one iteration ahead.
__global__ __launch_bounds__(256, 3) void pair2_kernel(
    const float* __restrict__ lbuf, const float* __restrict__ pbuf,
    const float* __restrict__ A1, const float* __restrict__ B1,
    const unsigned short* __restrict__ W1xf, const unsigned short* __restrict__ W2f,
    const float* __restrict__ b2, const float* __restrict__ W3,
    const float* __restrict__ b3, const unsigned char* __restrict__ lmask,
    const unsigned char* __restrict__ pmask, float* __restrict__ logits) {
  __shared__ float ltpt[2][24 * 68];  // rows 0..7 = l, 8..23 = p; pad 68
  __shared__ float U[8192];           // F frags (32KB), later H frags
  __shared__ float b2s[HD];
  __shared__ float w3s[HD];
  __shared__ float redbuf[128];

  const int tid = threadIdx.x;
  const int lane = tid & 63;
  const int w = tid >> 6;
  const int g = lane >> 4;
  const int c = lane & 15;
  const int wm = w >> 1;  // hid half
  const int wn = w & 1;   // ligand half
  const int bb = blockIdx.z;
  const int i0 = blockIdx.y * LB;
  const int j0 = blockIdx.x * PB;

  if (tid < 128) b2s[tid] = b2[tid];
  else w3s[tid - 128] = W3[tid - 128];

  // staging map: 384 f32x4 items (24 rows x 16 quads); thread does tid, tid+256
  const int srow = tid >> 4, sq = tid & 15;
  const int srow2 = (tid + 256) >> 4;

  auto gaddr = [&](int row, int q, int c4) -> const float* {
    return (row < 8)
        ? &lbuf[(size_t)(bb * LL + i0 + row) * BD + c4 * 64 + q * 4]
        : &pbuf[(size_t)(bb * LP + j0 + (row - 8)) * BD + c4 * 64 + q * 4];
  };

  // preload chunk 0
  {
    f32x4 r0 = {}, r1 = {};
    if (tid < 384) r0 = *(const f32x4*)gaddr(srow, sq, 0);
    if (tid < 128) r1 = *(const f32x4*)gaddr(srow2, sq, 0);
    if (tid < 384) *(f32x4*)&ltpt[0][srow * 68 + sq * 4] = r0;
    if (tid < 128) *(f32x4*)&ltpt[0][srow2 * 68 + sq * 4] = r1;
  }
  __syncthreads();

  f32x4 acc1[4][4];
#pragma unroll
  for (int m = 0; m < 4; ++m)
#pragma unroll
    for (int n = 0; n < 4; ++n) acc1[m][n] = (f32x4)0.0f;

  const unsigned short* Fush = (const unsigned short*)U;
  unsigned* Fdw = (unsigned*)U;

  for (int c4 = 0; c4 < 4; ++c4) {
    const int buf = c4 & 1;

    // prefetch type-0 (product) A-frags: cc = c4
    s16x8 afr0[2][4];
#pragma unroll
    for (int kt = 0; kt < 2; ++kt)
#pragma unroll
      for (int m = 0; m < 4; ++m)
        afr0[kt][m] = *(const s16x8*)(W1xf +
            ((size_t)((c4 * 2 + kt) * 8 + (wm * 4 + m)) * 64 + lane) * 8);

    // issue global loads for next chunk (regs)
    f32x4 r0 = {}, r1 = {};
    if (c4 < 3) {
      if (tid < 384) r0 = *(const f32x4*)gaddr(srow, sq, c4 + 1);
      if (tid < 128) r1 = *(const f32x4*)gaddr(srow2, sq, c4 + 1);
    }

    // build 32 F fragments: frag = t*16 + kt*8 + ntg (wave-uniform per f)
#pragma unroll
    for (int f = 0; f < 8; ++f) {
      const int frag = w + f * 4;
      const int t = frag >> 4, kt = (frag >> 3) & 1, ntg = frag & 7;
      const int kc0 = kt * 32 + g * 8;
      const float* lr = &ltpt[buf][ntg * 68 + kc0];
      const float* pr = &ltpt[buf][(8 + c) * 68 + kc0];
      f32x4 l0 = *(const f32x4*)lr;
      f32x4 l1 = *(const f32x4*)(lr + 4);
      f32x4 p0 = *(const f32x4*)pr;
      f32x4 p1 = *(const f32x4*)(pr + 4);
      float x[8];
      if (t == 0) {
#pragma unroll
        for (int q = 0; q < 4; ++q) { x[q] = l0[q] * p0[q]; x[4 + q] = l1[q] * p1[q]; }
      } else {
#pragma unroll
        for (int q = 0; q < 4; ++q) { x[q] = fabsf(l0[q] - p0[q]); x[4 + q] = fabsf(l1[q] - p1[q]); }
      }
      u32x4 pk;
      pk[0] = pack_bf16(x[0], x[1]);
      pk[1] = pack_bf16(x[2], x[3]);
      pk[2] = pack_bf16(x[4], x[5]);
      pk[3] = pack_bf16(x[6], x[7]);
      *(u32x4*)&Fdw[((size_t)frag * 64 + lane) * 4] = pk;
    }

    // commit next chunk's lt/pt
    if (c4 < 3) {
      const int nbuf = buf ^ 1;
      if (tid < 384) *(f32x4*)&ltpt[nbuf][srow * 68 + sq * 4] = r0;
      if (tid < 128) *(f32x4*)&ltpt[nbuf][srow2 * 68 + sq * 4] = r1;
    }
    __syncthreads();

    // type-1 (absdiff) A-frags: cc = 4 + c4 (hidden under type-0 MFMAs)
    s16x8 afr1[2][4];
#pragma unroll
    for (int kt = 0; kt < 2; ++kt)
#pragma unroll
      for (int m = 0; m < 4; ++m)
        afr1[kt][m] = *(const s16x8*)(W1xf +
            ((size_t)(((4 + c4) * 2 + kt) * 8 + (wm * 4 + m)) * 64 + lane) * 8);

#pragma unroll
    for (int kt = 0; kt < 2; ++kt)
#pragma unroll
      for (int n = 0; n < 4; ++n) {
        s16x8 bf = *((const s16x8*)Fush + ((kt * 8 + (wn * 4 + n)) * 64 + lane));
#pragma unroll
        for (int m = 0; m < 4; ++m) acc1[m][n] = mfma16(afr0[kt][m], bf, acc1[m][n]);
      }
#pragma unroll
    for (int kt = 0; kt < 2; ++kt)
#pragma unroll
      for (int n = 0; n < 4; ++n) {
        s16x8 bf = *((const s16x8*)Fush + ((16 + kt * 8 + (wn * 4 + n)) * 64 + lane));
#pragma unroll
        for (int m = 0; m < 4; ++m) acc1[m][n] = mfma16(afr1[kt][m], bf, acc1[m][n]);
      }
    __syncthreads();
  }

  // epilogue layer1: h = gelu(D1 + A1 + B1); write H (overlays F) in B-frag order
  unsigned* Hdw = (unsigned*)U;
#pragma unroll
  for (int m = 0; m < 4; ++m) {
    const int hidM = wm * 4 + m;
    const int kt2 = (4 * hidM + g) >> 3;
    const int l2 = ((2 * hidM + (g >> 1)) & 3) * 16 + c;
    const int jd = (g & 1) * 2;
#pragma unroll
    for (int n = 0; n < 4; ++n) {
      const int ntg = wn * 4 + n;
      f32x4 a1v = *(const f32x4*)&A1[(size_t)(bb * LL + i0 + ntg) * HD + hidM * 16 + g * 4];
      f32x4 b1v = *(const f32x4*)&B1[(size_t)(bb * LP + j0 + c) * HD + hidM * 16 + g * 4];
      float h0 = gelu_fast(acc1[m][n][0] + a1v[0] + b1v[0]);
      float h1 = gelu_fast(acc1[m][n][1] + a1v[1] + b1v[1]);
      float h2 = gelu_fast(acc1[m][n][2] + a1v[2] + b1v[2]);
      float h3 = gelu_fast(acc1[m][n][3] + a1v[3] + b1v[3]);
      int base = ((kt2 * 8 + ntg) * 64 + l2) * 4 + jd;
      Hdw[base] = pack_bf16(h0, h1);
      Hdw[base + 1] = pack_bf16(h2, h3);
    }
  }
  __syncthreads();

  // layer 2: D2 = W2^T @ H
  f32x4 acc2[4][4];
#pragma unroll
  for (int m = 0; m < 4; ++m)
#pragma unroll
    for (int n = 0; n < 4; ++n) acc2[m][n] = (f32x4)0.0f;

  const unsigned short* Hush = (const unsigned short*)U;
#pragma unroll
  for (int kt = 0; kt < 4; ++kt) {
    s16x8 a2[4];
#pragma unroll
    for (int m = 0; m < 4; ++m)
      a2[m] = *(const s16x8*)(W2f + (size_t)((kt * 8 + (wm * 4 + m)) * 64 + lane) * 8);
#pragma unroll
    for (int n = 0; n < 4; ++n) {
      s16x8 bf = *((const s16x8*)Hush + ((kt * 8 + (wn * 4 + n)) * 64 + lane));
#pragma unroll
      for (int m = 0; m < 4; ++m) acc2[m][n] = mfma16(a2[m], bf, acc2[m][n]);
    }
  }

  // layer3: gelu + dot W3, reduce over hid
  float partial[4] = {0.0f, 0.0f, 0.0f, 0.0f};
#pragma unroll
  for (int m = 0; m < 4; ++m) {
    const int hb = (wm * 4 + m) * 16 + g * 4;
    f32x4 b2v = *(const f32x4*)&b2s[hb];
    f32x4 w3v = *(const f32x4*)&w3s[hb];
#pragma unroll
    for (int n = 0; n < 4; ++n) {
#pragma unroll
      for (int r = 0; r < 4; ++r)
        partial[n] = fmaf(gelu_fast(acc2[m][n][r] + b2v[r]), w3v[r], partial[n]);
    }
  }
#pragma unroll
  for (int n = 0; n < 4; ++n) {
    partial[n] += __shfl_xor(partial[n], 16, 64);
    partial[n] += __shfl_xor(partial[n], 32, 64);
  }
  if (wm == 0 && g == 0) {
#pragma unroll
    for (int n = 0; n < 4; ++n) redbuf[wn * 64 + n * 16 + c] = partial[n];
  }
  __syncthreads();
  if (wm == 1 && g == 0) {
    const float bb3 = b3[0];
#pragma unroll
    for (int n = 0; n < 4; ++n) {
      const int ntg = wn * 4 + n;
      float v = partial[n] + redbuf[wn * 64 + n * 16 + c] + bb3;
      if (isnan(v)) v = 0.0f;
      else if (isinf(v)) v = (v > 0.0f) ? 20.0f : NEGV;
      const int i = i0 + ntg, j = j0 + c;
      if (lmask[bb * LL + i] || pmask[bb * LP + j]) v = NEGV;
      logits[(size_t)bb * LL * LP + i * LP + j] = v;
    }
  }
}

// ---------------- exact top-100 + softmax-weighted sum ----------------------
__device__ __forceinline__ unsigned int fkey(float f) {
  unsigned int u = __float_as_uint(f);
  return u ^ ((u >> 31) ? 0xFFFFFFFFu : 0x80000000u);
}
__device__ __forceinline__ float finv(unsigned int k) {
  unsigned int u = k ^ ((k >> 31) ? 0x80000000u : 0xFFFFFFFFu);
  return __uint_as_float(u);
}

__global__ __launch_bounds__(1024) void topk_kernel(const float* __restrict__ logits,
                                                    float* __restrict__ out) {
  const int N = LL * LP;
  const int b = blockIdx.x;
  const float* data = logits + (size_t)b * N;
  const int tid = threadIdx.x;
  __shared__ unsigned int hist[256];
  __shared__ unsigned int ured[1024];
  __shared__ float red[1024];
  __shared__ unsigned int sPrefix, sNeed;

  unsigned int km = 0u;
  for (int i = tid; i < N; i += 1024) km = max(km, fkey(data[i]));
  ured[tid] = km;
  __syncthreads();
  for (int s = 512; s > 0; s >>= 1) {
    if (tid < s) ured[tid] = max(ured[tid], ured[tid + s]);
    __syncthreads();
  }
  const float vmax = finv(ured[0]);

  if (tid == 0) { sPrefix = 0u; sNeed = 100u; }
  __syncthreads();

  for (int s = 24; s >= 0; s -= 8) {
    if (tid < 256) hist[tid] = 0u;
    __syncthreads();
    const unsigned int prefix = sPrefix;
    const unsigned int maskhi = (s == 24) ? 0u : (0xFFFFFFFFu << (s + 8));
    for (int i = tid; i < N; i += 1024) {
      unsigned int k = fkey(data[i]);
      if ((k & maskhi) == (prefix & maskhi)) atomicAdd(&hist[(k >> s) & 255], 1u);
    }
    __syncthreads();
    if (tid == 0) {
      unsigned int need = sNeed, cum = 0u;
      int dsel = 0;
      for (int d = 255; d >= 0; --d) {
        cum += hist[d];
        if (cum >= need) { dsel = d; break; }
      }
      sNeed = need - (cum - hist[dsel]);
      sPrefix = prefix | ((unsigned int)dsel << s);
    }
    __syncthreads();
  }
  const unsigned int Tkey = sPrefix;
  const unsigned int needT = sNeed;
  const float T = finv(Tkey);

  float s1 = 0.0f, s2 = 0.0f;
  for (int i = tid; i < N; i += 1024) {
    float v = data[i];
    if (fkey(v) > Tkey) {
      float e = expf(v - vmax);
      s1 += e;
      s2 = fmaf(e, v, s2);
    }
  }
  red[tid] = s1;
  __syncthreads();
  for (int s = 512; s > 0; s >>= 1) {
    if (tid < s) red[tid] += red[tid + s];
    __syncthreads();
  }
  float s1t = red[0];
  __syncthreads();
  red[tid] = s2;
  __syncthreads();
  for (int s = 512; s > 0; s >>= 1) {
    if (tid < s) red[tid] += red[tid + s];
    __syncthreads();
  }
  if (tid == 0) {
    float s2t = red[0];
    float e = expf(T - vmax);
    float denom = s1t + (float)needT * e;
    float num = s2t + (float)needT * e * T;
    out[b] = num / denom;
  }
}

// ---------------------------------------------------------------------------
extern "C" void kernel_launch(void* const* d_in, const int* in_sizes, int n_in,
                              void* d_out, int out_size, void* d_ws, size_t ws_size,
                              hipStream_t stream) {
  const float* l_tok = (const float*)d_in[0];
  const float* p_tok = (const float*)d_in[1];
  const void* l_pad = d_in[2];
  const void* p_pad = d_in[3];
  const float* Wl = (const float*)d_in[4];
  const float* bl = (const float*)d_in[5];
  const float* Wp = (const float*)d_in[6];
  const float* bp = (const float*)d_in[7];
  const float* W1 = (const float*)d_in[8];
  const float* b1 = (const float*)d_in[9];
  const float* W2 = (const float*)d_in[10];
  const float* b2 = (const float*)d_in[11];
  const float* W3 = (const float*)d_in[12];
  const float* b3 = (const float*)d_in[13];

  float* ws = (float*)d_ws;
  float* wl_ = ws;                    // [2,96,256]   49152
  float* wp_ = ws + 49152;            // [2,768,256]  393216
  float* wA = ws + 442368;            // A1: [2,96,128]
  float* wB = ws + 466944;            // B1: [2,768,128]
  float* wLog = ws + 663552;          // logits [2,73728]
  unsigned char* lmask = (unsigned char*)(ws + 811008);
  unsigned char* pmask = lmask + NB * LL;
  unsigned short* W1xf = (unsigned short*)(ws + 811520);  // 65536 u16
  unsigned short* W2f = (unsigned short*)(ws + 844288);   // 16384 u16

  decode_swz_kernel<<<321, 256, 0, stream>>>(l_pad, p_pad, lmask, pmask,
                                             W1, W2, W1xf, W2f);
  fused_proj_kernel<<<NB * (LL + LP) / 16, 256, 0, stream>>>(
      l_tok, p_tok, Wl, bl, Wp, bp, W1, b1, wl_, wp_, wA, wB);

  dim3 grid(LP / PB, LL / LB, NB);
  pair2_kernel<<<grid, 256, 0, stream>>>(wl_, wp_, wA, wB, W1xf, W2f,
                                         b2, W3, b3, lmask, pmask, wLog);
  topk_kernel<<<NB, 1024, 0, stream>>>(wLog, (float*)d_out);
}